// Round 8
// baseline (1179.577 us; speedup 1.0000x reference)
//
#include <hip/hip_runtime.h>
#include <cmath>

#define N_NODES 50000
#define N_EDGES 800000
#define F_IN 92
#define DIM 64
#define EF 50
#define NLAYER 3
#define NGRAPH 128
#define ZROWS 178   // 2*DIM + EF

// ---------------- pre FC: h = relu(x @ pre_W + pre_b) ----------------
__global__ __launch_bounds__(256, 3) void pre_fc(const float* __restrict__ x,
                                                 const float* __restrict__ W,
                                                 const float* __restrict__ b,
                                                 float* __restrict__ h, int N)
{
    const int lane = threadIdx.x & 63;
    const int wid  = blockIdx.x * (blockDim.x >> 6) + (threadIdx.x >> 6);
    const int nw   = gridDim.x * (blockDim.x >> 6);
    float w[F_IN];
#pragma unroll
    for (int k = 0; k < F_IN; ++k) w[k] = W[k * DIM + lane];
    const float bb = b[lane];
#pragma unroll 1
    for (int n = wid; n < N; n += nw) {
        const int nu = __builtin_amdgcn_readfirstlane(n);
        const float* xr = x + (size_t)nu * F_IN;
        float a = bb;
#pragma unroll
        for (int k = 0; k < F_IN; ++k) a = fmaf(xr[k], w[k], a);
        h[(size_t)nu * DIM + lane] = fmaxf(a, 0.f);
    }
}

// ---------------- histogram of dst (int) + graph-node counts ----------------
__global__ __launch_bounds__(256) void hist_cnt(const int* __restrict__ ei, int E,
                                                const int* __restrict__ batch, int N,
                                                int* __restrict__ hist,
                                                float* __restrict__ cnt)
{
    const int i = blockIdx.x * blockDim.x + threadIdx.x;
    const int stride = gridDim.x * blockDim.x;
    for (int e = i; e < E; e += stride) atomicAdd(&hist[ei[E + e]], 1);
    for (int n = i; n < N; n += stride) unsafeAtomicAdd(&cnt[batch[n]], 1.f);
}

// ---------------- exclusive scan of hist -> offs (single block) ----------------
__global__ __launch_bounds__(256) void scan_offs(const int* __restrict__ hist,
                                                 int* __restrict__ offs, int Nn)
{
    __shared__ int ssum[256];
    const int t = threadIdx.x;
    const int seg = (Nn + 255) / 256;
    const int lo = t * seg;
    const int hi = (lo + seg < Nn) ? lo + seg : Nn;
    int s = 0;
    for (int i = lo; i < hi; ++i) s += hist[i];
    ssum[t] = s;
    __syncthreads();
    if (t == 0) {
        int run = 0;
        for (int i = 0; i < 256; ++i) { int v = ssum[i]; ssum[i] = run; run += v; }
        offs[Nn] = run;
    }
    __syncthreads();
    int run = ssum[t];
    for (int i = lo; i < hi; ++i) { offs[i] = run; run += hist[i]; }
}

// ---------------- scatter edges into dst-sorted order ----------------
__global__ __launch_bounds__(256) void scatter_edges(const int* __restrict__ ei,
                                                     const int* __restrict__ offs,
                                                     int* __restrict__ cursor,
                                                     int* __restrict__ s_src,
                                                     int* __restrict__ s_dst,
                                                     int* __restrict__ s_eid, int E)
{
    const int i = blockIdx.x * blockDim.x + threadIdx.x;
    const int stride = gridDim.x * blockDim.x;
    for (int e = i; e < E; e += stride) {
        const int d = ei[E + e];
        const int s = ei[e];
        const int pos = offs[d] + atomicAdd(&cursor[d], 1);
        s_src[pos] = s;
        s_dst[pos] = d;
        s_eid[pos] = e;
    }
}

// ---------------- node projections for layer l ----------------
// Pd[n] = [ h@Wf[0:64] + bf | h@Ws[0:64] + bs ]   (dst/i, biases folded)
// Ps[n] = [ h@Wf[64:128]    | h@Ws[64:128]     ]  (src/j)
__global__ __launch_bounds__(256, 2) void node_proj(const float* __restrict__ h,
                                                    const float* __restrict__ Wfl,
                                                    const float* __restrict__ Wsl,
                                                    const float* __restrict__ bf,
                                                    const float* __restrict__ bs,
                                                    float* __restrict__ Pd,
                                                    float* __restrict__ Ps, int N)
{
    const int lane = threadIdx.x & 63;
    const int wid  = blockIdx.x * (blockDim.x >> 6) + (threadIdx.x >> 6);
    const int nw   = gridDim.x * (blockDim.x >> 6);
    const int half = wid & 1;  // 0 -> Pd, 1 -> Ps
    const float* wfb = Wfl + (half ? DIM * DIM : 0);
    const float* wsb = Wsl + (half ? DIM * DIM : 0);
    float wf[DIM], ws[DIM];
#pragma unroll
    for (int k = 0; k < DIM; ++k) { wf[k] = wfb[k * DIM + lane]; ws[k] = wsb[k * DIM + lane]; }
    const float b0 = half ? 0.f : bf[lane];
    const float b1 = half ? 0.f : bs[lane];
    float* P = half ? Ps : Pd;
#pragma unroll 1
    for (int n = (wid >> 1); n < N; n += (nw >> 1)) {
        const int nu = __builtin_amdgcn_readfirstlane(n);
        const float* hr = h + (size_t)nu * DIM;
        float a0 = b0, a1 = b1;
#pragma unroll
        for (int k = 0; k < DIM; ++k) {
            const float v = hr[k];
            a0 = fmaf(v, wf[k], a0);
            a1 = fmaf(v, ws[k], a1);
        }
        P[(size_t)nu * 128 + lane]      = a0;
        P[(size_t)nu * 128 + 64 + lane] = a1;
    }
}

// ---------------- fused edge kernel over dst-sorted edges ----------------
// One block = 512 threads (8 waves) = one tile of 64 sorted edges.
// Phase A: eattr projection, lane=edge, weights via wave-uniform s_loads.
// Phase B: lane=dim, 8 sequential sorted edges per wave; register-accumulate
//   the message while dst is unchanged (wave-uniform branch), flush once per
//   run with one atomicAdd; Pd row hoisted per run.
#define EA_PAD 51
#define TP_PAD 129
__global__ __launch_bounds__(512) void edge_fused(const int* __restrict__ s_src,
                                                  const int* __restrict__ s_dst,
                                                  const int* __restrict__ s_eid,
                                                  const float* __restrict__ eattr,
                                                  const float* __restrict__ Pd,
                                                  const float* __restrict__ Ps,
                                                  const float* __restrict__ WfE,
                                                  const float* __restrict__ WsE,
                                                  float* __restrict__ agg, int E)
{
    __shared__ float ea_lds[64 * EA_PAD];
    __shared__ float out_lds[64 * TP_PAD];

    const int tid = threadIdx.x;
    const int e0  = blockIdx.x * 64;

    // ---- stage 64 (gathered) eattr rows ----
    {
        const int* eid = s_eid + e0;
        for (int idx = tid; idx < 64 * EF; idx += 512) {
            const int e = idx / EF;
            const int k = idx - e * EF;
            ea_lds[e * EA_PAD + k] = eattr[(size_t)eid[e] * EF + k];
        }
    }
    __syncthreads();

    // ---- phase A: projection, lane = edge, 16 cols per wave ----
    {
        const int e  = tid & 63;
        const int wv = __builtin_amdgcn_readfirstlane(tid >> 6);  // 0..7 uniform
        const float* Wbase = (wv < 4) ? WfE : WsE;   // uniform pointer
        const int c0 = (wv & 3) * 16;                // uniform col offset in [0,64)
        const int cb = ((wv < 4) ? 0 : 64) + c0;     // output col base in [0,128)

        float acc[16];
#pragma unroll
        for (int j = 0; j < 16; ++j) acc[j] = 0.f;

        const float* ear = ea_lds + e * EA_PAD;
#pragma unroll 5
        for (int k = 0; k < EF; ++k) {
            const float eak = ear[k];                 // ds_read, conflict-free
            const float* wr = Wbase + k * DIM + c0;   // uniform -> s_load
#pragma unroll
            for (int j = 0; j < 16; ++j) acc[j] = fmaf(eak, wr[j], acc[j]);
        }
        float* orow = out_lds + e * TP_PAD + cb;
#pragma unroll
        for (int j = 0; j < 16; ++j) orow[j] = acc[j];
    }
    __syncthreads();

    // ---- phase B: gate + run-accumulated scatter, lane = dim ----
    {
        const int lane = tid & 63;
        const int wv   = __builtin_amdgcn_readfirstlane(tid >> 6);
        const int base = e0 + wv * 8;

        int dcur = s_dst[base];                       // uniform
        const float* pdr = Pd + (size_t)dcur * 128;
        float pd0 = pdr[lane], pd1 = pdr[64 + lane];
        float acc = 0.f;
#pragma unroll
        for (int i = 0; i < 8; ++i) {
            const int el = wv * 8 + i;
            const int eg = base + i;
            const int dd = s_dst[eg];                 // uniform
            const int ss = s_src[eg];                 // uniform
            if (dd != dcur) {                         // wave-uniform branch
                unsafeAtomicAdd(&agg[(size_t)dcur * DIM + lane], acc);
                acc = 0.f;
                dcur = dd;
                pdr = Pd + (size_t)dcur * 128;
                pd0 = pdr[lane]; pd1 = pdr[64 + lane];
            }
            const float* psr = Ps + (size_t)ss * 128;
            const float zf = out_lds[el * TP_PAD + lane]      + pd0 + psr[lane];
            const float zs = out_lds[el * TP_PAD + 64 + lane] + pd1 + psr[64 + lane];
            const float sig = 1.f / (1.f + __expf(-zf));
            const float sp  = fmaxf(zs, 0.f) + __logf(1.f + __expf(-fabsf(zs)));
            acc = fmaf(sig, sp, acc);
        }
        unsafeAtomicAdd(&agg[(size_t)dcur * DIM + lane], acc);
    }
}

// ---------------- node update: h = BN(h + agg/deg) ----------------
__global__ __launch_bounds__(256) void node_update(float* __restrict__ h,
                                                   const float* __restrict__ agg,
                                                   const int* __restrict__ hist,
                                                   const float* __restrict__ gamma,
                                                   const float* __restrict__ beta,
                                                   const float* __restrict__ mean,
                                                   const float* __restrict__ var, int N)
{
    const int lane = threadIdx.x & 63;
    const float g  = gamma[lane];
    const float bt = beta[lane];
    const float mn = mean[lane];
    const float iv = rsqrtf(var[lane] + 1e-5f);
    const int idx = blockIdx.x * blockDim.x + threadIdx.x;
    const int stride = gridDim.x * blockDim.x;  // multiple of 64
    const int total = N * DIM;
    for (int i = idx; i < total; i += stride) {
        const int n = i >> 6;
        const float inv = 1.f / fmaxf((float)hist[n], 1.f);
        const float v = h[i] + agg[i] * inv;
        h[i] = fmaf(g, (v - mn) * iv, bt);
    }
}

// ---------------- global mean pool (sum part) ----------------
__global__ __launch_bounds__(256) void pool_sum(const float* __restrict__ h,
                                                const int* __restrict__ batch,
                                                float* __restrict__ gsum, int N)
{
    const int lane = threadIdx.x & 63;
    const int wid  = blockIdx.x * (blockDim.x >> 6) + (threadIdx.x >> 6);
    const int nw   = gridDim.x * (blockDim.x >> 6);
    for (int n = wid; n < N; n += nw) {
        const int nu = __builtin_amdgcn_readfirstlane(n);
        const int b = batch[nu];
        unsafeAtomicAdd(&gsum[(size_t)b * DIM + lane], h[(size_t)nu * DIM + lane]);
    }
}

// ---------------- head: g=relu(mean@postW+postb); out = g@outW+outb ----------------
__global__ __launch_bounds__(64) void head(const float* __restrict__ gsum,
                                           const float* __restrict__ cnt,
                                           const float* __restrict__ postW,
                                           const float* __restrict__ postb,
                                           const float* __restrict__ outW,
                                           const float* __restrict__ outb,
                                           float* __restrict__ out)
{
    const int gi = blockIdx.x;
    const int lane = threadIdx.x;
    const float inv = 1.f / fmaxf(cnt[gi], 1.f);
    const float gval = gsum[(size_t)gi * DIM + lane] * inv;
    float acc = postb[lane];
#pragma unroll
    for (int k = 0; k < DIM; ++k) acc = fmaf(__shfl(gval, k, 64), postW[k * DIM + lane], acc);
    const float t = fmaxf(acc, 0.f);
    float prod = t * outW[lane];
#pragma unroll
    for (int off = 32; off > 0; off >>= 1) prod += __shfl_down(prod, off, 64);
    if (lane == 0) out[gi] = prod + outb[0];
}

extern "C" void kernel_launch(void* const* d_in, const int* in_sizes, int n_in,
                              void* d_out, int out_size, void* d_ws, size_t ws_size,
                              hipStream_t stream)
{
    const float* x     = (const float*)d_in[0];
    const int*   ei    = (const int*)d_in[1];
    const float* eattr = (const float*)d_in[2];
    const int*   batch = (const int*)d_in[3];
    const float* preW  = (const float*)d_in[4];
    const float* preb  = (const float*)d_in[5];
    const float* Wf    = (const float*)d_in[6];
    const float* bf    = (const float*)d_in[7];
    const float* Ws    = (const float*)d_in[8];
    const float* bs    = (const float*)d_in[9];
    const float* gamma = (const float*)d_in[10];
    const float* beta  = (const float*)d_in[11];
    const float* mean  = (const float*)d_in[12];
    const float* var   = (const float*)d_in[13];
    const float* postW = (const float*)d_in[14];
    const float* postb = (const float*)d_in[15];
    const float* outW  = (const float*)d_in[16];
    const float* outb  = (const float*)d_in[17];
    float* out = (float*)d_out;

    const int N = N_NODES, E = N_EDGES, G = NGRAPH;

    char* p = (char*)d_ws;
    float* h      = (float*)p; p += (size_t)N * DIM * 4;
    float* Pd     = (float*)p; p += (size_t)N * 128 * 4;
    float* Ps     = (float*)p; p += (size_t)N * 128 * 4;
    float* agg    = (float*)p; p += (size_t)N * DIM * 4;
    // zeroed-together block: gsum | cnt | hist | cursor
    float* gsum   = (float*)p; p += (size_t)G * DIM * 4;
    float* cnt    = (float*)p; p += (size_t)G * 4;
    int*   hist   = (int*)p;   p += (size_t)N * 4;
    int*   cursor = (int*)p;   p += (size_t)N * 4;
    int*   offs   = (int*)p;   p += (size_t)(N + 1) * 4;
    int*   s_src  = (int*)p;   p += (size_t)E * 4;
    int*   s_dst  = (int*)p;   p += (size_t)E * 4;
    int*   s_eid  = (int*)p;   p += (size_t)E * 4;

    hipMemsetAsync(gsum, 0, ((size_t)G * DIM + G + N + N) * 4, stream);

    hist_cnt<<<512, 256, 0, stream>>>(ei, E, batch, N, hist, cnt);
    scan_offs<<<1, 256, 0, stream>>>(hist, offs, N);
    scatter_edges<<<512, 256, 0, stream>>>(ei, offs, cursor, s_src, s_dst, s_eid, E);

    pre_fc<<<512, 256, 0, stream>>>(x, preW, preb, h, N);

    for (int l = 0; l < NLAYER; ++l) {
        const float* Wfl = Wf + (size_t)l * ZROWS * DIM;
        const float* Wsl = Ws + (size_t)l * ZROWS * DIM;
        hipMemsetAsync(agg, 0, (size_t)N * DIM * 4, stream);
        node_proj<<<512, 256, 0, stream>>>(h, Wfl, Wsl, bf + l * DIM, bs + l * DIM, Pd, Ps, N);
        edge_fused<<<E / 64, 512, 0, stream>>>(s_src, s_dst, s_eid, eattr, Pd, Ps,
                                               Wfl + 2 * DIM * DIM, Wsl + 2 * DIM * DIM, agg, E);
        node_update<<<1024, 256, 0, stream>>>(h, agg, hist, gamma + l * DIM, beta + l * DIM,
                                              mean + l * DIM, var + l * DIM, N);
    }

    pool_sum<<<512, 256, 0, stream>>>(h, batch, gsum, N);
    head<<<G, 64, 0, stream>>>(gsum, cnt, postW, postb, outW, outb, out);
}